// Round 9
// baseline (983.970 us; speedup 1.0000x reference)
//
#include <hip/hip_runtime.h>
#include <hip/hip_bf16.h>

// GCN 2-layer forward for MI355X (gfx950).
// Dtype detected on-device (f32 vs bf16 harness conversion), inside kconvw.
// Rows pre-scaled by dinv so aggregation is a plain sum.
// Pipeline (no fine sort at all):
//   kpart : edges -> etmp[bk*CAP+slot] packed (src<<7)|dstlow, bucket-grouped
//   kfine : per bucket: LDS histogram of dstlow -> dinv only (no sort!)
//   kgemm1: h1s = (x @ W1) * dinv, bf16, MFMA
//   kagg1 : block per bucket; every lane = independent 8B gather of a row
//           slice; ds_add_f32 into 128x65 LDS acc (fire-and-forget, no
//           divergence, 64 loads in flight/wave — fixes R5's starvation);
//           epilogue relu+bias then MFMA GEMM2 -> h2sb bf16
//   kagg2 : same structure on 32B rows; width-8 softmax epilogue -> out

typedef unsigned short u16;
typedef __attribute__((ext_vector_type(8))) short short8;   // 8 bf16
typedef __attribute__((ext_vector_type(4))) float f32x4;

#define CAP 4096    // bucket capacity: Binomial(1.6M, 1/782) ~ 2046 +- 45
#define ACCW 65     // LDS acc row stride (f32) — spreads atomic banks

__device__ __forceinline__ float bf2f(u16 u) {
  return __uint_as_float(((unsigned int)u) << 16);
}
__device__ __forceinline__ u16 f2bf(float f) {
  unsigned int u = __float_as_uint(f);
  u += 0x7fffu + ((u >> 16) & 1u);
  return (u16)(u >> 16);
}

// ---- weight canonicalization + integrated dtype detect ----
__global__ __launch_bounds__(256) void kconvw(const void* __restrict__ W1r,
                                              const void* __restrict__ b1r,
                                              const void* __restrict__ W2r,
                                              const void* __restrict__ b2r,
                                              u16* __restrict__ W1b,
                                              float* __restrict__ b1f,
                                              u16* __restrict__ W2b,
                                              float* __restrict__ b2f,
                                              int* __restrict__ mode) {
  __shared__ float red[4];
  __shared__ int smode;
  const u16* w = (const u16*)W1r;
  float mx = 0.f;
  for (int i = threadIdx.x; i < 8192; i += 256) {
    float av = fabsf(bf2f(w[i]));
    if (!(av <= 1e6f)) av = 3e38f;
    mx = fmaxf(mx, av);
  }
  #pragma unroll
  for (int off = 32; off >= 1; off >>= 1) mx = fmaxf(mx, __shfl_xor(mx, off, 64));
  if ((threadIdx.x & 63) == 0) red[threadIdx.x >> 6] = mx;
  __syncthreads();
  if (threadIdx.x == 0) {
    float m2 = fmaxf(fmaxf(red[0], red[1]), fmaxf(red[2], red[3]));
    smode = (m2 > 1e6f) ? 1 : 0;
    if (blockIdx.x == 0) mode[0] = smode;
  }
  __syncthreads();
  int m = smode;
  int gid = blockIdx.x * 256 + threadIdx.x, stride = gridDim.x * 256;
  for (int i = gid; i < 8192; i += stride)
    W1b[i] = m ? f2bf(((const float*)W1r)[i]) : ((const u16*)W1r)[i];
  for (int i = gid; i < 1024; i += stride)
    W2b[i] = m ? f2bf(((const float*)W2r)[i]) : ((const u16*)W2r)[i];
  for (int i = gid; i < 64; i += stride)
    b1f[i] = m ? ((const float*)b1r)[i] : bf2f(((const u16*)b1r)[i]);
  for (int i = gid; i < 16; i += stride)
    b2f[i] = m ? ((const float*)b2r)[i] : bf2f(((const u16*)b2r)[i]);
}

// Partition edges into padded buckets (8192 edges/block, 512 threads).
__global__ __launch_bounds__(512) void kpart(const int* __restrict__ src,
                                             const int* __restrict__ dst,
                                             int* __restrict__ cursor,
                                             int* __restrict__ etmp,
                                             int E, int NB) {
  __shared__ int hist[1024], basep[1024];
  int tid = threadIdx.x;
  for (int i = tid; i < 1024; i += 512) hist[i] = 0;
  __syncthreads();
  int e0 = blockIdx.x * 8192 + tid * 16;
  int pk[16], off[16], cb[16];
  if (e0 + 15 < E) {
    int4 s4[4], d4[4];
    #pragma unroll
    for (int u = 0; u < 4; ++u) {
      s4[u] = ((const int4*)(src + e0))[u];
      d4[u] = ((const int4*)(dst + e0))[u];
    }
    const int* sp = (const int*)s4;
    const int* dp = (const int*)d4;
    #pragma unroll
    for (int k = 0; k < 16; ++k) {
      int s = sp[k], d = dp[k];
      cb[k] = d >> 7;
      pk[k] = (s << 7) | (d & 127);
      off[k] = atomicAdd(&hist[cb[k]], 1);
    }
  } else {
    #pragma unroll
    for (int k = 0; k < 16; ++k) {
      int e = e0 + k;
      cb[k] = -1;
      if (e < E) {
        int s = src[e], d = dst[e];
        cb[k] = d >> 7;
        pk[k] = (s << 7) | (d & 127);
        off[k] = atomicAdd(&hist[cb[k]], 1);
      }
    }
  }
  __syncthreads();
  for (int i = tid; i < NB; i += 512)
    if (hist[i]) basep[i] = atomicAdd(&cursor[i], hist[i]);
  __syncthreads();
  if (e0 + 15 < E) {
    #pragma unroll
    for (int k = 0; k < 16; ++k)
      etmp[cb[k] * CAP + basep[cb[k]] + off[k]] = pk[k];
  } else {
    #pragma unroll
    for (int k = 0; k < 16; ++k)
      if (cb[k] >= 0) etmp[cb[k] * CAP + basep[cb[k]] + off[k]] = pk[k];
  }
}

// Per bucket: dst_low histogram -> dinv. No sort, no write-back.
__global__ __launch_bounds__(512) void kfine(const int* __restrict__ etmp,
                                             const int* __restrict__ cursor,
                                             float* __restrict__ dinv, int N) {
  __shared__ int hist[128];
  int bk = blockIdx.x, tid = threadIdx.x;
  int cnt = cursor[bk], base = bk * CAP;
  if (tid < 128) hist[tid] = 0;
  __syncthreads();
  for (int i = tid; i < cnt; i += 512)
    atomicAdd(&hist[etmp[base + i] & 127], 1);
  __syncthreads();
  int node = (bk << 7) + tid;
  if (tid < 128 && node < N)
    dinv[node] = rsqrtf((float)(hist[tid] + 1));
}

// h1s = (x @ W1) * dinv[row], bf16 out. One wave per 16-row tile.
__global__ __launch_bounds__(256) void kgemm1(const void* __restrict__ xraw,
                                              const u16* __restrict__ W1b,
                                              const int* __restrict__ mode,
                                              const float* __restrict__ dinv,
                                              u16* __restrict__ h1s, int n) {
  int mflag = mode[0];
  int wid = blockIdx.x * 4 + (threadIdx.x >> 6);
  int row0 = wid * 16;
  if (row0 >= n) return;
  int lane = threadIdx.x & 63;
  int m = lane & 15, q = lane >> 4;

  short8 bfrag[4][4];
  for (int jb = 0; jb < 4; ++jb)
    for (int kb = 0; kb < 4; ++kb) {
      short8 f;
      #pragma unroll
      for (int j = 0; j < 8; ++j)
        f[j] = (short)W1b[(kb * 32 + q * 8 + j) * 64 + jb * 16 + m];
      bfrag[jb][kb] = f;
    }

  f32x4 acc[4];
  #pragma unroll
  for (int jb = 0; jb < 4; ++jb) acc[jb] = (f32x4){0.f, 0.f, 0.f, 0.f};

  #pragma unroll
  for (int kb = 0; kb < 4; ++kb) {
    short8 a;
    if (mflag) {
      const float* xf = (const float*)xraw + (size_t)(row0 + m) * 128 + kb * 32 + q * 8;
      float4 u0 = ((const float4*)xf)[0];
      float4 u1 = ((const float4*)xf)[1];
      // packed f32->bf16 (v_cvt_pk_bf16_f32 when available)
      __hip_bfloat162 p0 = __float22bfloat162_rn(make_float2(u0.x, u0.y));
      __hip_bfloat162 p1 = __float22bfloat162_rn(make_float2(u0.z, u0.w));
      __hip_bfloat162 p2 = __float22bfloat162_rn(make_float2(u1.x, u1.y));
      __hip_bfloat162 p3 = __float22bfloat162_rn(make_float2(u1.z, u1.w));
      unsigned int w0 = *(const unsigned int*)&p0;
      unsigned int w1 = *(const unsigned int*)&p1;
      unsigned int w2 = *(const unsigned int*)&p2;
      unsigned int w3 = *(const unsigned int*)&p3;
      a[0] = (short)(w0 & 0xffff); a[1] = (short)(w0 >> 16);
      a[2] = (short)(w1 & 0xffff); a[3] = (short)(w1 >> 16);
      a[4] = (short)(w2 & 0xffff); a[5] = (short)(w2 >> 16);
      a[6] = (short)(w3 & 0xffff); a[7] = (short)(w3 >> 16);
    } else {
      a = *(const short8*)((const u16*)xraw + (size_t)(row0 + m) * 128 + kb * 32 + q * 8);
    }
    #pragma unroll
    for (int jb = 0; jb < 4; ++jb)
      acc[jb] = __builtin_amdgcn_mfma_f32_16x16x32_bf16(a, bfrag[jb][kb], acc[jb], 0, 0, 0);
  }

  #pragma unroll
  for (int r = 0; r < 4; ++r) {
    float dv = dinv[row0 + q * 4 + r];
    #pragma unroll
    for (int jb = 0; jb < 4; ++jb)
      h1s[(row0 + q * 4 + r) * 64 + jb * 16 + m] = f2bf(acc[jb][r] * dv);
  }
}

// Layer-1: block per bucket. Every lane independently gathers an 8B slice of
// a source row (16 lanes = 128B row) and ds_add_f32's into LDS acc. Epilogue:
// relu+bias in LDS, then MFMA GEMM2 (A=relu1 from LDS, B=W2 bf16) -> h2sb.
__global__ __launch_bounds__(512) void kagg1(
    const u16* __restrict__ h1s, const int* __restrict__ etmp,
    const int* __restrict__ cursor, const float* __restrict__ dinv,
    const float* __restrict__ b1f, const u16* __restrict__ W2b,
    u16* __restrict__ h2sb, int N) {
  __shared__ float acc[128 * ACCW];      // 33280 B
  __shared__ float sdinv[128];
  int tid = threadIdx.x;
  int bk = blockIdx.x;
  int base = bk * CAP;
  int cnt = cursor[bk];
  int node0 = bk << 7;
  int nn = min(128, N - node0);

  for (int i = tid; i < 128 * ACCW; i += 512) acc[i] = 0.f;
  if (tid < 128) sdinv[tid] = (tid < nn) ? dinv[node0 + tid] : 0.f;

  // B-frags for the GEMM2 MFMA (W2b row-major [k][c]; lane&15 = class col)
  int lane = tid & 63, wv = tid >> 6;
  int m16 = lane & 15, q = lane >> 4;
  short8 bf0, bf1;
  #pragma unroll
  for (int j = 0; j < 8; ++j) {
    bf0[j] = (short)W2b[(q * 8 + j) * 16 + m16];
    bf1[j] = (short)W2b[(32 + q * 8 + j) * 16 + m16];
  }
  __syncthreads();

  // edge pass: task t -> edge t>>4, dword-slice ql = t&15
  int ql = tid & 15;
  const uint2* h1v = (const uint2*)h1s;
  int T = cnt << 4;
  for (int t = tid; t < T; t += 512) {
    int pk = etmp[base + (t >> 4)];       // 16-lane broadcast load
    int s = pk >> 7, dl = pk & 127;
    uint2 g = h1v[s * 16 + ql];
    float* ap = &acc[dl * ACCW + (ql << 2)];
    atomicAdd(ap + 0, bf2f((u16)(g.x & 0xffff)));
    atomicAdd(ap + 1, bf2f((u16)(g.x >> 16)));
    atomicAdd(ap + 2, bf2f((u16)(g.y & 0xffff)));
    atomicAdd(ap + 3, bf2f((u16)(g.y >> 16)));
  }
  __syncthreads();

  // epilogue 1: v = relu(dinv*(acc + self) + b1), in place (4 threads/node)
  {
    int n = tid >> 2, q4 = tid & 3;
    if (n < nn) {
      float dv = sdinv[n];
      const uint2* selfp = &h1v[(node0 + n) * 16 + q4 * 4];
      float* ap = &acc[n * ACCW + q4 * 16];
      #pragma unroll
      for (int j = 0; j < 4; ++j) {
        uint2 g = selfp[j];
        float4 bv = ((const float4*)b1f)[q4 * 4 + j];
        ap[4 * j + 0] = fmaxf(dv * (ap[4 * j + 0] + bf2f((u16)(g.x & 0xffff))) + bv.x, 0.f);
        ap[4 * j + 1] = fmaxf(dv * (ap[4 * j + 1] + bf2f((u16)(g.x >> 16))) + bv.y, 0.f);
        ap[4 * j + 2] = fmaxf(dv * (ap[4 * j + 2] + bf2f((u16)(g.y & 0xffff))) + bv.z, 0.f);
        ap[4 * j + 3] = fmaxf(dv * (ap[4 * j + 3] + bf2f((u16)(g.y >> 16))) + bv.w, 0.f);
      }
    }
  }
  __syncthreads();

  // epilogue 2: GEMM2 via MFMA. Wave wv handles nodes [wv*16, wv*16+16).
  // A[m=lane&15][k=q*8+j] from LDS acc; D: col=lane&15=class, row=q*4+r=node.
  {
    int gbase = wv * 16;
    const float* arow = &acc[(gbase + m16) * ACCW];
    short8 a0, a1;
    #pragma unroll
    for (int j = 0; j < 8; ++j) {
      a0[j] = (short)f2bf(arow[q * 8 + j]);
      a1[j] = (short)f2bf(arow[32 + q * 8 + j]);
    }
    f32x4 c = (f32x4){0.f, 0.f, 0.f, 0.f};
    c = __builtin_amdgcn_mfma_f32_16x16x32_bf16(a0, bf0, c, 0, 0, 0);
    c = __builtin_amdgcn_mfma_f32_16x16x32_bf16(a1, bf1, c, 0, 0, 0);
    #pragma unroll
    for (int r = 0; r < 4; ++r) {
      int n = gbase + q * 4 + r;
      if (n < nn)
        h2sb[(node0 + n) * 16 + m16] = f2bf(c[r] * sdinv[n]);
    }
  }
}

// Layer-2: block per bucket; 8 lanes/edge dword gathers; ds_add into
// 128x17 LDS acc; epilogue bias+relu+log_softmax (width-8) -> out.
__global__ __launch_bounds__(512) void kagg2(
    const u16* __restrict__ h2sb, const int* __restrict__ etmp,
    const int* __restrict__ cursor, const float* __restrict__ dinv,
    const float* __restrict__ b2f, const int* __restrict__ mode,
    void* __restrict__ out, int N) {
  __shared__ float acc[128 * 17];        // 8704 B
  __shared__ float sdinv[128];
  int mflag = mode[0];
  int tid = threadIdx.x;
  int bk = blockIdx.x;
  int base = bk * CAP;
  int cnt = cursor[bk];
  int node0 = bk << 7;
  int nn = min(128, N - node0);

  for (int i = tid; i < 128 * 17; i += 512) acc[i] = 0.f;
  if (tid < 128) sdinv[tid] = (tid < nn) ? dinv[node0 + tid] : 0.f;
  __syncthreads();

  int ol = tid & 7;
  const unsigned int* h2v = (const unsigned int*)h2sb;   // 8 dwords/row
  int T = cnt << 3;
  for (int t = tid; t < T; t += 512) {
    int pk = etmp[base + (t >> 3)];       // 8-lane broadcast load
    int s = pk >> 7, dl = pk & 127;
    unsigned int g = h2v[s * 8 + ol];
    float* ap = &acc[dl * 17 + (ol << 1)];
    atomicAdd(ap + 0, bf2f((u16)(g & 0xffff)));
    atomicAdd(ap + 1, bf2f((u16)(g >> 16)));
  }
  __syncthreads();

  // epilogue: 8 lanes per node, 2 passes of 64 nodes
  float2 b2v = ((const float2*)b2f)[ol];
  #pragma unroll
  for (int pass = 0; pass < 2; ++pass) {
    int n = pass * 64 + (tid >> 3);
    float dv = sdinv[n];
    unsigned int sg = h2v[(node0 + ((n < nn) ? n : 0)) * 8 + ol];
    float vx = fmaxf(dv * (acc[n * 17 + 2 * ol] + bf2f((u16)(sg & 0xffff))) + b2v.x, 0.f);
    float vy = fmaxf(dv * (acc[n * 17 + 2 * ol + 1] + bf2f((u16)(sg >> 16))) + b2v.y, 0.f);
    float m = fmaxf(vx, vy);
    #pragma unroll
    for (int off = 1; off <= 4; off <<= 1) m = fmaxf(m, __shfl_xor(m, off, 8));
    float ex = __expf(vx - m) + __expf(vy - m);
    #pragma unroll
    for (int off = 1; off <= 4; off <<= 1) ex += __shfl_xor(ex, off, 8);
    float lg = __logf(ex);
    float rx = vx - m - lg, ry = vy - m - lg;
    if (n < nn) {
      size_t oidx = (size_t)(node0 + n) * 8 + ol;
      if (mflag) ((float2*)out)[oidx] = make_float2(rx, ry);
      else ((unsigned int*)out)[oidx] =
             (unsigned int)f2bf(rx) | ((unsigned int)f2bf(ry) << 16);
    }
  }
}

extern "C" void kernel_launch(void* const* d_in, const int* in_sizes, int n_in,
                              void* d_out, int out_size, void* d_ws, size_t ws_size,
                              hipStream_t stream) {
  const void* x  = d_in[0];
  const int* ei  = (const int*)d_in[1];
  const void* W1 = d_in[2];
  const void* b1 = d_in[3];
  const void* W2 = d_in[4];
  const void* b2 = d_in[5];

  const int N = in_sizes[0] / 128;
  const int E = in_sizes[1] / 2;
  const int* src = ei;
  const int* dst = ei + E;
  const int NB = (N + 127) >> 7;          // 128-node buckets

  char* ws = (char*)d_ws;
  size_t off = 0;
  auto alloc = [&](size_t bytes) -> char* {
    char* p = ws + off;
    off = (off + bytes + 255) & ~(size_t)255;
    return p;
  };
  u16*   h1s    = (u16*)  alloc((size_t)N * 64 * 2);
  u16*   h2sb   = (u16*)  alloc((size_t)N * 16 * 2);
  int*   etmp   = (int*)  alloc((size_t)NB * CAP * 4);
  float* dinv   = (float*)alloc((size_t)N * 4);
  int*   cursor = (int*)  alloc((size_t)NB * 4);
  u16*   W1b    = (u16*)  alloc(8192 * 2);
  u16*   W2b    = (u16*)  alloc(1024 * 2);
  float* b1f    = (float*)alloc(64 * 4);
  float* b2f    = (float*)alloc(16 * 4);
  int*   mode   = (int*)  alloc(4);

  hipMemsetAsync(cursor, 0, (size_t)NB * 4, stream);

  kconvw<<<32, 256, 0, stream>>>(W1, b1, W2, b2, W1b, b1f, W2b, b2f, mode);

  kpart<<<(E + 8191) / 8192, 512, 0, stream>>>(src, dst, cursor, etmp, E, NB);
  kfine<<<NB, 512, 0, stream>>>(etmp, cursor, dinv, N);

  int tiles = (N + 15) / 16;
  kgemm1<<<(tiles + 3) / 4, 256, 0, stream>>>(x, W1b, mode, dinv, h1s, N);
  kagg1<<<NB, 512, 0, stream>>>(h1s, etmp, cursor, dinv, b1f, W2b, h2sb, N);
  kagg2<<<NB, 512, 0, stream>>>(h2sb, etmp, cursor, dinv, b2f, mode, d_out, N);
}

// Round 10
// 204.875 us; speedup vs baseline: 4.8028x; 4.8028x over previous
//
#include <hip/hip_runtime.h>
#include <hip/hip_bf16.h>

// GCN 2-layer forward for MI355X (gfx950).
// Dtype detected on-device (f32 vs bf16 harness conversion), inside kconvw.
// Rows pre-scaled by dinv so aggregation is a plain sum.
// LESSON (R5, R9): LDS-atomic scatter aggregation (~102M ds_add) is ~10x
// slower than register accumulation — aggregation stays register-based.
// Pipeline:
//   kpart : edges -> etmp[bk*CAP+slot] packed (src<<7)|dstlow, bucket-grouped
//   kfine : per bucket: histogram -> dinv only
//   kgemm1: h1s = (x @ W1) * dinv, bf16, MFMA
//   kagg1f: block per bucket: LDS counting sort (staging->eS) then R8's
//           quarter-wave register-accumulation gather from LDS-sorted list;
//           MFMA GEMM2 epilogue (wave-private LDS tile, no block barrier);
//           writes h2sb + sorted esort + rowse for layer 2
//   kagg2 : oct-per-node gather (R8) + width-8 log_softmax -> out

typedef unsigned short u16;
typedef __attribute__((ext_vector_type(8))) short short8;   // 8 bf16
typedef __attribute__((ext_vector_type(4))) float f32x4;

#define CAP 4096    // bucket capacity: Binomial(1.6M, 1/782) ~ 2046 +- 45

__device__ __forceinline__ float bf2f(u16 u) {
  return __uint_as_float(((unsigned int)u) << 16);
}
__device__ __forceinline__ u16 f2bf(float f) {
  unsigned int u = __float_as_uint(f);
  u += 0x7fffu + ((u >> 16) & 1u);
  return (u16)(u >> 16);
}

// ---- weight canonicalization + integrated dtype detect ----
__global__ __launch_bounds__(256) void kconvw(const void* __restrict__ W1r,
                                              const void* __restrict__ b1r,
                                              const void* __restrict__ W2r,
                                              const void* __restrict__ b2r,
                                              u16* __restrict__ W1b,
                                              float* __restrict__ b1f,
                                              u16* __restrict__ W2b,
                                              float* __restrict__ b2f,
                                              int* __restrict__ mode) {
  __shared__ float red[4];
  __shared__ int smode;
  const u16* w = (const u16*)W1r;
  float mx = 0.f;
  for (int i = threadIdx.x; i < 8192; i += 256) {
    float av = fabsf(bf2f(w[i]));
    if (!(av <= 1e6f)) av = 3e38f;
    mx = fmaxf(mx, av);
  }
  #pragma unroll
  for (int off = 32; off >= 1; off >>= 1) mx = fmaxf(mx, __shfl_xor(mx, off, 64));
  if ((threadIdx.x & 63) == 0) red[threadIdx.x >> 6] = mx;
  __syncthreads();
  if (threadIdx.x == 0) {
    float m2 = fmaxf(fmaxf(red[0], red[1]), fmaxf(red[2], red[3]));
    smode = (m2 > 1e6f) ? 1 : 0;
    if (blockIdx.x == 0) mode[0] = smode;
  }
  __syncthreads();
  int m = smode;
  int gid = blockIdx.x * 256 + threadIdx.x, stride = gridDim.x * 256;
  for (int i = gid; i < 8192; i += stride)
    W1b[i] = m ? f2bf(((const float*)W1r)[i]) : ((const u16*)W1r)[i];
  for (int i = gid; i < 1024; i += stride)
    W2b[i] = m ? f2bf(((const float*)W2r)[i]) : ((const u16*)W2r)[i];
  for (int i = gid; i < 64; i += stride)
    b1f[i] = m ? ((const float*)b1r)[i] : bf2f(((const u16*)b1r)[i]);
  for (int i = gid; i < 16; i += stride)
    b2f[i] = m ? ((const float*)b2r)[i] : bf2f(((const u16*)b2r)[i]);
}

// Partition edges into padded buckets (8192 edges/block, 512 threads).
__global__ __launch_bounds__(512) void kpart(const int* __restrict__ src,
                                             const int* __restrict__ dst,
                                             int* __restrict__ cursor,
                                             int* __restrict__ etmp,
                                             int E, int NB) {
  __shared__ int hist[1024], basep[1024];
  int tid = threadIdx.x;
  for (int i = tid; i < 1024; i += 512) hist[i] = 0;
  __syncthreads();
  int e0 = blockIdx.x * 8192 + tid * 16;
  int pk[16], off[16], cb[16];
  if (e0 + 15 < E) {
    int4 s4[4], d4[4];
    #pragma unroll
    for (int u = 0; u < 4; ++u) {
      s4[u] = ((const int4*)(src + e0))[u];
      d4[u] = ((const int4*)(dst + e0))[u];
    }
    const int* sp = (const int*)s4;
    const int* dp = (const int*)d4;
    #pragma unroll
    for (int k = 0; k < 16; ++k) {
      int s = sp[k], d = dp[k];
      cb[k] = d >> 7;
      pk[k] = (s << 7) | (d & 127);
      off[k] = atomicAdd(&hist[cb[k]], 1);
    }
  } else {
    #pragma unroll
    for (int k = 0; k < 16; ++k) {
      int e = e0 + k;
      cb[k] = -1;
      if (e < E) {
        int s = src[e], d = dst[e];
        cb[k] = d >> 7;
        pk[k] = (s << 7) | (d & 127);
        off[k] = atomicAdd(&hist[cb[k]], 1);
      }
    }
  }
  __syncthreads();
  for (int i = tid; i < NB; i += 512)
    if (hist[i]) basep[i] = atomicAdd(&cursor[i], hist[i]);
  __syncthreads();
  if (e0 + 15 < E) {
    #pragma unroll
    for (int k = 0; k < 16; ++k)
      etmp[cb[k] * CAP + basep[cb[k]] + off[k]] = pk[k];
  } else {
    #pragma unroll
    for (int k = 0; k < 16; ++k)
      if (cb[k] >= 0) etmp[cb[k] * CAP + basep[cb[k]] + off[k]] = pk[k];
  }
}

// Per bucket: dst_low histogram -> dinv only.
__global__ __launch_bounds__(512) void kfine(const int* __restrict__ etmp,
                                             const int* __restrict__ cursor,
                                             float* __restrict__ dinv, int N) {
  __shared__ int hist[128];
  int bk = blockIdx.x, tid = threadIdx.x;
  int cnt = cursor[bk], base = bk * CAP;
  if (tid < 128) hist[tid] = 0;
  __syncthreads();
  for (int i = tid; i < cnt; i += 512)
    atomicAdd(&hist[etmp[base + i] & 127], 1);
  __syncthreads();
  int node = (bk << 7) + tid;
  if (tid < 128 && node < N)
    dinv[node] = rsqrtf((float)(hist[tid] + 1));
}

// h1s = (x @ W1) * dinv[row], bf16 out. One wave per 16-row tile.
__global__ __launch_bounds__(256) void kgemm1(const void* __restrict__ xraw,
                                              const u16* __restrict__ W1b,
                                              const int* __restrict__ mode,
                                              const float* __restrict__ dinv,
                                              u16* __restrict__ h1s, int n) {
  int mflag = mode[0];
  int wid = blockIdx.x * 4 + (threadIdx.x >> 6);
  int row0 = wid * 16;
  if (row0 >= n) return;
  int lane = threadIdx.x & 63;
  int m = lane & 15, q = lane >> 4;

  short8 bfrag[4][4];
  for (int jb = 0; jb < 4; ++jb)
    for (int kb = 0; kb < 4; ++kb) {
      short8 f;
      #pragma unroll
      for (int j = 0; j < 8; ++j)
        f[j] = (short)W1b[(kb * 32 + q * 8 + j) * 64 + jb * 16 + m];
      bfrag[jb][kb] = f;
    }

  f32x4 acc[4];
  #pragma unroll
  for (int jb = 0; jb < 4; ++jb) acc[jb] = (f32x4){0.f, 0.f, 0.f, 0.f};

  #pragma unroll
  for (int kb = 0; kb < 4; ++kb) {
    short8 a;
    if (mflag) {
      const float* xf = (const float*)xraw + (size_t)(row0 + m) * 128 + kb * 32 + q * 8;
      float4 u0 = ((const float4*)xf)[0];
      float4 u1 = ((const float4*)xf)[1];
      __hip_bfloat162 p0 = __float22bfloat162_rn(make_float2(u0.x, u0.y));
      __hip_bfloat162 p1 = __float22bfloat162_rn(make_float2(u0.z, u0.w));
      __hip_bfloat162 p2 = __float22bfloat162_rn(make_float2(u1.x, u1.y));
      __hip_bfloat162 p3 = __float22bfloat162_rn(make_float2(u1.z, u1.w));
      unsigned int w0 = *(const unsigned int*)&p0;
      unsigned int w1 = *(const unsigned int*)&p1;
      unsigned int w2 = *(const unsigned int*)&p2;
      unsigned int w3 = *(const unsigned int*)&p3;
      a[0] = (short)(w0 & 0xffff); a[1] = (short)(w0 >> 16);
      a[2] = (short)(w1 & 0xffff); a[3] = (short)(w1 >> 16);
      a[4] = (short)(w2 & 0xffff); a[5] = (short)(w2 >> 16);
      a[6] = (short)(w3 & 0xffff); a[7] = (short)(w3 >> 16);
    } else {
      a = *(const short8*)((const u16*)xraw + (size_t)(row0 + m) * 128 + kb * 32 + q * 8);
    }
    #pragma unroll
    for (int jb = 0; jb < 4; ++jb)
      acc[jb] = __builtin_amdgcn_mfma_f32_16x16x32_bf16(a, bfrag[jb][kb], acc[jb], 0, 0, 0);
  }

  #pragma unroll
  for (int r = 0; r < 4; ++r) {
    float dv = dinv[row0 + q * 4 + r];
    #pragma unroll
    for (int jb = 0; jb < 4; ++jb)
      h1s[(row0 + q * 4 + r) * 64 + jb * 16 + m] = f2bf(acc[jb][r] * dv);
  }
}

// Fused sort + layer-1 aggregate + MFMA GEMM2. Block = bucket (512 thr).
__global__ __launch_bounds__(512) void kagg1f(
    const u16* __restrict__ h1s, const int* __restrict__ etmp,
    const int* __restrict__ cursor, const float* __restrict__ dinv,
    const float* __restrict__ b1f, const u16* __restrict__ W2b,
    int* __restrict__ esort, int2* __restrict__ rowse,
    u16* __restrict__ h2sb, int N) {
  __shared__ int eL[CAP];                 // staging; reused as f32 rows tile
  __shared__ int eS[CAP];                 // sorted src indices
  __shared__ int hist[128], starts[128], curs[128];
  __shared__ float sdinv[128];

  int tid = threadIdx.x;
  int bk = blockIdx.x;
  int base = bk * CAP;
  int cnt = cursor[bk];
  int node0 = bk << 7;

  if (tid < 128) {
    hist[tid] = 0;
    int nd = node0 + tid;
    sdinv[tid] = (nd < N) ? dinv[nd] : 0.f;
  }
  __syncthreads();
  for (int i = tid; i < cnt; i += 512) {
    int pk = etmp[base + i];
    eL[i] = pk;
    atomicAdd(&hist[pk & 127], 1);
  }
  __syncthreads();
  if (tid < 64) {
    int v0 = hist[tid], v1 = hist[tid + 64];
    int s0 = v0;
    #pragma unroll
    for (int off = 1; off < 64; off <<= 1) {
      int t = __shfl_up(s0, off, 64);
      if (tid >= off) s0 += t;
    }
    int tot0 = __shfl(s0, 63, 64);
    int s1 = v1;
    #pragma unroll
    for (int off = 1; off < 64; off <<= 1) {
      int t = __shfl_up(s1, off, 64);
      if (tid >= off) s1 += t;
    }
    s1 += tot0;
    int e0x = s0 - v0, e1x = s1 - v1;
    starts[tid] = e0x;  curs[tid] = e0x;
    starts[tid + 64] = e1x;  curs[tid + 64] = e1x;
    int n0 = node0 + tid, n1 = n0 + 64;
    if (n0 < N) rowse[n0] = make_int2(base + e0x, base + e0x + v0);
    if (n1 < N) rowse[n1] = make_int2(base + e1x, base + e1x + v1);
  }
  __syncthreads();
  for (int i = tid; i < cnt; i += 512) {
    int pk = eL[i];
    int pos = atomicAdd(&curs[pk & 127], 1);
    int sidx = pk >> 7;
    eS[pos] = sidx;
    esort[base + pos] = sidx;            // dense [base, base+cnt), L2-assembled
  }

  // GEMM2 B-frags (W2b row-major [k][class]); lane&15 = class column.
  int lane = tid & 63, wv = tid >> 6;
  int m16 = lane & 15, q = lane >> 4;    // also (ql, quarter) for gather
  short8 bw0, bw1;
  #pragma unroll
  for (int j = 0; j < 8; ++j) {
    bw0[j] = (short)W2b[(q * 8 + j) * 16 + m16];
    bw1[j] = (short)W2b[(32 + q * 8 + j) * 16 + m16];
  }
  __syncthreads();                        // eS/starts/hist final; eL now free

  float* rowsL = (float*)eL;              // [32 rows][68 stride] f32 (8.5 KB)
  const uint2* h1v = (const uint2*)h1s;   // 16 uint2 per 64-feat row
  int ql = m16;

  for (int pass = 0; pass < 4; ++pass) {
    int nl = pass * 32 + wv * 4 + q;      // local node handled by this quarter
    int nd = node0 + nl;
    int cn = (nd < N) ? nd : node0;       // clamped address
    int rs = starts[nl], deg = hist[nl];
    float a0 = 0.f, a1 = 0.f, a2 = 0.f, a3 = 0.f;
    int k = rs, ke = rs + deg;
    for (; k + 8 <= ke; k += 8) {         // 8 independent gathers in flight
      int sI[8];
      uint2 g[8];
      #pragma unroll
      for (int p = 0; p < 8; ++p) sI[p] = eS[k + p];
      #pragma unroll
      for (int p = 0; p < 8; ++p) g[p] = h1v[sI[p] * 16 + ql];
      #pragma unroll
      for (int p = 0; p < 8; ++p) {
        a0 += bf2f((u16)(g[p].x & 0xffff));
        a1 += bf2f((u16)(g[p].x >> 16));
        a2 += bf2f((u16)(g[p].y & 0xffff));
        a3 += bf2f((u16)(g[p].y >> 16));
      }
    }
    for (; k < ke; ++k) {
      int s = eS[k];
      uint2 g = h1v[s * 16 + ql];
      a0 += bf2f((u16)(g.x & 0xffff));
      a1 += bf2f((u16)(g.x >> 16));
      a2 += bf2f((u16)(g.y & 0xffff));
      a3 += bf2f((u16)(g.y >> 16));
    }
    uint2 sg = h1v[cn * 16 + ql];
    float dv = sdinv[nl];
    float4 bv = ((const float4*)b1f)[ql];
    float4 vr;
    vr.x = fmaxf(dv * (a0 + bf2f((u16)(sg.x & 0xffff))) + bv.x, 0.f);
    vr.y = fmaxf(dv * (a1 + bf2f((u16)(sg.x >> 16))) + bv.y, 0.f);
    vr.z = fmaxf(dv * (a2 + bf2f((u16)(sg.y & 0xffff))) + bv.z, 0.f);
    vr.w = fmaxf(dv * (a3 + bf2f((u16)(sg.y >> 16))) + bv.w, 0.f);

    // stage relu1 into the wave's PRIVATE 4-row tile (wave-local only)
    *(float4*)&rowsL[(wv * 4 + q) * 68 + 4 * ql] = vr;
    __builtin_amdgcn_wave_barrier();      // order LDS write->read in-wave

    // A-frag: lane (m16=node row, q=k-quarter); rows >=4 are zero.
    const float* ar = &rowsL[(wv * 4 + (m16 & 3)) * 68];
    bool rv = (m16 < 4);
    short8 af0, af1;
    #pragma unroll
    for (int j = 0; j < 8; ++j) {
      af0[j] = rv ? (short)f2bf(ar[q * 8 + j]) : (short)0;
      af1[j] = rv ? (short)f2bf(ar[32 + q * 8 + j]) : (short)0;
    }
    f32x4 c = (f32x4){0.f, 0.f, 0.f, 0.f};
    c = __builtin_amdgcn_mfma_f32_16x16x32_bf16(af0, bw0, c, 0, 0, 0);
    c = __builtin_amdgcn_mfma_f32_16x16x32_bf16(af1, bw1, c, 0, 0, 0);
    // D: col=lane&15=class, row=q*4+r=node-in-tile (valid rows 0..3 -> q==0)
    if (q == 0) {
      #pragma unroll
      for (int r = 0; r < 4; ++r) {
        int nl2 = pass * 32 + wv * 4 + r;
        int nd2 = node0 + nl2;
        if (nd2 < N) h2sb[nd2 * 16 + m16] = f2bf(c[r] * sdinv[nl2]);
      }
    }
    __builtin_amdgcn_wave_barrier();      // keep next pass's write after reads
  }
}

// Layer-2 aggregate + bias + relu + log_softmax (R8 structure).
// OCT per node: ol=lane&7 owns classes 2ol..2ol+1; 8 edges/load-instr.
__global__ __launch_bounds__(256) void kagg2(
    const u16* __restrict__ h2sb, const int* __restrict__ esort,
    const int2* __restrict__ rowse, const float* __restrict__ dinv,
    const float* __restrict__ b2f, const int* __restrict__ mode,
    void* __restrict__ out, int n) {
  int mflag = mode[0];
  int tid = threadIdx.x;
  int lane = tid & 63, wv = tid >> 6;
  int ol = lane & 7, oc = lane >> 3;
  int node = blockIdx.x * 32 + wv * 8 + oc;
  if (node >= n) node = n - 1;
  int2 se = rowse[node];
  int beg = se.x, end = se.y;
  const unsigned int* h2v = (const unsigned int*)h2sb;   // 8 dwords/row
  unsigned int sg = h2v[node * 8 + ol];
  float ax = 0.f, ay = 0.f;

  for (int base = beg; base < end; base += 8) {
    int idx = base + ol;
    int eidx = esort[(idx < end) ? idx : (end - 1)];     // 8-wide
    int cnt = min(8, end - base);
    int k = 0;
    for (; k + 8 <= cnt; k += 8) {
      unsigned int g[8];
      #pragma unroll
      for (int p = 0; p < 8; ++p) {
        int s = __shfl(eidx, k + p, 8);
        g[p] = h2v[s * 8 + ol];
      }
      #pragma unroll
      for (int p = 0; p < 8; ++p) {
        ax += bf2f((u16)(g[p] & 0xffff));
        ay += bf2f((u16)(g[p] >> 16));
      }
    }
    for (; k < cnt; ++k) {
      int s = __shfl(eidx, k, 8);
      unsigned int g = h2v[s * 8 + ol];
      ax += bf2f((u16)(g & 0xffff));
      ay += bf2f((u16)(g >> 16));
    }
  }

  float dv = dinv[node];
  float2 b2v = ((const float2*)b2f)[ol];
  float vx = fmaxf(dv * (ax + bf2f((u16)(sg & 0xffff))) + b2v.x, 0.f);
  float vy = fmaxf(dv * (ay + bf2f((u16)(sg >> 16))) + b2v.y, 0.f);

  float m = fmaxf(vx, vy);
  #pragma unroll
  for (int off = 1; off <= 4; off <<= 1) m = fmaxf(m, __shfl_xor(m, off, 8));
  float ex = __expf(vx - m) + __expf(vy - m);
  #pragma unroll
  for (int off = 1; off <= 4; off <<= 1) ex += __shfl_xor(ex, off, 8);
  float lg = __logf(ex);
  float rx = vx - m - lg, ry = vy - m - lg;
  if (mflag) ((float2*)out)[(size_t)node * 8 + ol] = make_float2(rx, ry);
  else ((unsigned int*)out)[(size_t)node * 8 + ol] =
         (unsigned int)f2bf(rx) | ((unsigned int)f2bf(ry) << 16);
}

extern "C" void kernel_launch(void* const* d_in, const int* in_sizes, int n_in,
                              void* d_out, int out_size, void* d_ws, size_t ws_size,
                              hipStream_t stream) {
  const void* x  = d_in[0];
  const int* ei  = (const int*)d_in[1];
  const void* W1 = d_in[2];
  const void* b1 = d_in[3];
  const void* W2 = d_in[4];
  const void* b2 = d_in[5];

  const int N = in_sizes[0] / 128;
  const int E = in_sizes[1] / 2;
  const int* src = ei;
  const int* dst = ei + E;
  const int NB = (N + 127) >> 7;          // 128-node buckets

  char* ws = (char*)d_ws;
  size_t off = 0;
  auto alloc = [&](size_t bytes) -> char* {
    char* p = ws + off;
    off = (off + bytes + 255) & ~(size_t)255;
    return p;
  };
  u16*   h1s    = (u16*)  alloc((size_t)N * 64 * 2);
  u16*   h2sb   = (u16*)  alloc((size_t)N * 16 * 2);
  int*   etmp   = (int*)  alloc((size_t)NB * CAP * 4);
  int*   esort  = (int*)  alloc((size_t)NB * CAP * 4);
  int2*  rowse  = (int2*) alloc((size_t)N * 8);
  float* dinv   = (float*)alloc((size_t)N * 4);
  int*   cursor = (int*)  alloc((size_t)NB * 4);
  u16*   W1b    = (u16*)  alloc(8192 * 2);
  u16*   W2b    = (u16*)  alloc(1024 * 2);
  float* b1f    = (float*)alloc(64 * 4);
  float* b2f    = (float*)alloc(16 * 4);
  int*   mode   = (int*)  alloc(4);

  hipMemsetAsync(cursor, 0, (size_t)NB * 4, stream);

  kconvw<<<32, 256, 0, stream>>>(W1, b1, W2, b2, W1b, b1f, W2b, b2f, mode);

  kpart<<<(E + 8191) / 8192, 512, 0, stream>>>(src, dst, cursor, etmp, E, NB);
  kfine<<<NB, 512, 0, stream>>>(etmp, cursor, dinv, N);

  int tiles = (N + 15) / 16;
  kgemm1<<<(tiles + 3) / 4, 256, 0, stream>>>(x, W1b, mode, dinv, h1s, N);
  kagg1f<<<NB, 512, 0, stream>>>(h1s, etmp, cursor, dinv, b1f, W2b,
                                 esort, rowse, h2sb, N);
  kagg2<<<(N + 31) / 32, 256, 0, stream>>>(h2sb, esort, rowse, dinv, b2f, mode,
                                           d_out, N);
}

// Round 12
// 197.575 us; speedup vs baseline: 4.9802x; 1.0369x over previous
//
#include <hip/hip_runtime.h>
#include <hip/hip_bf16.h>

// GCN 2-layer forward for MI355X (gfx950).
// Dtype detected on-device (f32 vs bf16 harness conversion), inside kpartc b0.
// Rows pre-scaled by dinv so aggregation is a plain sum.
// LESSONS: (R5,R9) LDS-atomic scatter aggregation is ~10x slower than register
// accumulation. (R10) fusing the per-bucket counting sort into the gather
// kernel beats a split sort kernel. (R11) rowsL staging tile must be indexed
// WAVE-LOCALLY (wv*4+q), not by bucket-node index — nl*68 overflows eL and
// corrupts the sort tables -> wild global reads -> crash.
// Pipeline:
//   kpartc: block0 = weight canonicalization + dtype detect; other blocks
//           partition edges -> etmp[bk*CAP+slot] packed (src<<7)|dstlow
//   kfine : per bucket histogram -> dinv
//   kgemm1: h1s = (x @ W1) * dinv, bf16, MFMA
//   kagg1f: block per bucket: LDS counting sort -> eS; quarter-wave per node
//           register gather, uint4 16B/lane, 8 lanes/row, edge-PAIRS (2 edges
//           per load instr); MFMA GEMM2 epilogue -> h2sb; emits esort+rowse
//   kagg2 : oct per node, uint2 slice, edge-pairs; width-4 softmax -> out

typedef unsigned short u16;
typedef __attribute__((ext_vector_type(8))) short short8;   // 8 bf16
typedef __attribute__((ext_vector_type(4))) float f32x4;

#define CAP 4096    // bucket capacity: Binomial(1.6M, 1/782) ~ 2046 +- 45

__device__ __forceinline__ float bf2f(u16 u) {
  return __uint_as_float(((unsigned int)u) << 16);
}
__device__ __forceinline__ u16 f2bf(float f) {
  unsigned int u = __float_as_uint(f);
  u += 0x7fffu + ((u >> 16) & 1u);
  return (u16)(u >> 16);
}

// ---- merged: block 0 = weight canonicalization + dtype detect;
//      blocks 1.. = edge partition into padded buckets (8192 edges/block) ----
__global__ __launch_bounds__(512) void kpartc(
    const int* __restrict__ src, const int* __restrict__ dst,
    int* __restrict__ cursor, int* __restrict__ etmp,
    const void* __restrict__ W1r, const void* __restrict__ b1r,
    const void* __restrict__ W2r, const void* __restrict__ b2r,
    u16* __restrict__ W1b, float* __restrict__ b1f, u16* __restrict__ W2b,
    float* __restrict__ b2f, int* __restrict__ mode, int E, int NB) {
  __shared__ int hist[1024], basep[1024];
  __shared__ float red[8];
  __shared__ int smode;
  int tid = threadIdx.x;

  if (blockIdx.x == 0) {
    // ---- conv role ----
    const u16* w = (const u16*)W1r;
    float mx = 0.f;
    for (int i = tid; i < 8192; i += 512) {
      float av = fabsf(bf2f(w[i]));
      if (!(av <= 1e6f)) av = 3e38f;
      mx = fmaxf(mx, av);
    }
    #pragma unroll
    for (int off = 32; off >= 1; off >>= 1) mx = fmaxf(mx, __shfl_xor(mx, off, 64));
    if ((tid & 63) == 0) red[tid >> 6] = mx;
    __syncthreads();
    if (tid == 0) {
      float m2 = 0.f;
      #pragma unroll
      for (int wv = 0; wv < 8; ++wv) m2 = fmaxf(m2, red[wv]);
      smode = (m2 > 1e6f) ? 1 : 0;
      mode[0] = smode;
    }
    __syncthreads();
    int m = smode;
    for (int i = tid; i < 8192; i += 512)
      W1b[i] = m ? f2bf(((const float*)W1r)[i]) : ((const u16*)W1r)[i];
    for (int i = tid; i < 1024; i += 512)
      W2b[i] = m ? f2bf(((const float*)W2r)[i]) : ((const u16*)W2r)[i];
    if (tid < 64) b1f[tid] = m ? ((const float*)b1r)[tid] : bf2f(((const u16*)b1r)[tid]);
    if (tid < 16) b2f[tid] = m ? ((const float*)b2r)[tid] : bf2f(((const u16*)b2r)[tid]);
    return;
  }

  // ---- partition role ----
  for (int i = tid; i < 1024; i += 512) hist[i] = 0;
  __syncthreads();
  int e0 = (blockIdx.x - 1) * 8192 + tid * 16;
  int pk[16], off[16], cb[16];
  if (e0 + 15 < E) {
    int4 s4[4], d4[4];
    #pragma unroll
    for (int u = 0; u < 4; ++u) {
      s4[u] = ((const int4*)(src + e0))[u];
      d4[u] = ((const int4*)(dst + e0))[u];
    }
    const int* sp = (const int*)s4;
    const int* dp = (const int*)d4;
    #pragma unroll
    for (int k = 0; k < 16; ++k) {
      int s = sp[k], d = dp[k];
      cb[k] = d >> 7;
      pk[k] = (s << 7) | (d & 127);
      off[k] = atomicAdd(&hist[cb[k]], 1);
    }
  } else {
    #pragma unroll
    for (int k = 0; k < 16; ++k) {
      int e = e0 + k;
      cb[k] = -1;
      if (e < E) {
        int s = src[e], d = dst[e];
        cb[k] = d >> 7;
        pk[k] = (s << 7) | (d & 127);
        off[k] = atomicAdd(&hist[cb[k]], 1);
      }
    }
  }
  __syncthreads();
  for (int i = tid; i < NB; i += 512)
    if (hist[i]) basep[i] = atomicAdd(&cursor[i], hist[i]);
  __syncthreads();
  if (e0 + 15 < E) {
    #pragma unroll
    for (int k = 0; k < 16; ++k)
      etmp[cb[k] * CAP + basep[cb[k]] + off[k]] = pk[k];
  } else {
    #pragma unroll
    for (int k = 0; k < 16; ++k)
      if (cb[k] >= 0) etmp[cb[k] * CAP + basep[cb[k]] + off[k]] = pk[k];
  }
}

// Per bucket: dst_low histogram -> dinv only.
__global__ __launch_bounds__(512) void kfine(const int* __restrict__ etmp,
                                             const int* __restrict__ cursor,
                                             float* __restrict__ dinv, int N) {
  __shared__ int hist[128];
  int bk = blockIdx.x, tid = threadIdx.x;
  int cnt = cursor[bk], base = bk * CAP;
  if (tid < 128) hist[tid] = 0;
  __syncthreads();
  for (int i = tid; i < cnt; i += 512)
    atomicAdd(&hist[etmp[base + i] & 127], 1);
  __syncthreads();
  int node = (bk << 7) + tid;
  if (tid < 128 && node < N)
    dinv[node] = rsqrtf((float)(hist[tid] + 1));
}

// h1s = (x @ W1) * dinv[row], bf16 out. One wave per 16-row tile.
__global__ __launch_bounds__(256) void kgemm1(const void* __restrict__ xraw,
                                              const u16* __restrict__ W1b,
                                              const int* __restrict__ mode,
                                              const float* __restrict__ dinv,
                                              u16* __restrict__ h1s, int n) {
  int mflag = mode[0];
  int wid = blockIdx.x * 4 + (threadIdx.x >> 6);
  int row0 = wid * 16;
  if (row0 >= n) return;
  int lane = threadIdx.x & 63;
  int m = lane & 15, q = lane >> 4;

  short8 bfrag[4][4];
  for (int jb = 0; jb < 4; ++jb)
    for (int kb = 0; kb < 4; ++kb) {
      short8 f;
      #pragma unroll
      for (int j = 0; j < 8; ++j)
        f[j] = (short)W1b[(kb * 32 + q * 8 + j) * 64 + jb * 16 + m];
      bfrag[jb][kb] = f;
    }

  f32x4 acc[4];
  #pragma unroll
  for (int jb = 0; jb < 4; ++jb) acc[jb] = (f32x4){0.f, 0.f, 0.f, 0.f};

  #pragma unroll
  for (int kb = 0; kb < 4; ++kb) {
    short8 a;
    if (mflag) {
      const float* xf = (const float*)xraw + (size_t)(row0 + m) * 128 + kb * 32 + q * 8;
      float4 u0 = ((const float4*)xf)[0];
      float4 u1 = ((const float4*)xf)[1];
      __hip_bfloat162 p0 = __float22bfloat162_rn(make_float2(u0.x, u0.y));
      __hip_bfloat162 p1 = __float22bfloat162_rn(make_float2(u0.z, u0.w));
      __hip_bfloat162 p2 = __float22bfloat162_rn(make_float2(u1.x, u1.y));
      __hip_bfloat162 p3 = __float22bfloat162_rn(make_float2(u1.z, u1.w));
      unsigned int w0 = *(const unsigned int*)&p0;
      unsigned int w1 = *(const unsigned int*)&p1;
      unsigned int w2 = *(const unsigned int*)&p2;
      unsigned int w3 = *(const unsigned int*)&p3;
      a[0] = (short)(w0 & 0xffff); a[1] = (short)(w0 >> 16);
      a[2] = (short)(w1 & 0xffff); a[3] = (short)(w1 >> 16);
      a[4] = (short)(w2 & 0xffff); a[5] = (short)(w2 >> 16);
      a[6] = (short)(w3 & 0xffff); a[7] = (short)(w3 >> 16);
    } else {
      a = *(const short8*)((const u16*)xraw + (size_t)(row0 + m) * 128 + kb * 32 + q * 8);
    }
    #pragma unroll
    for (int jb = 0; jb < 4; ++jb)
      acc[jb] = __builtin_amdgcn_mfma_f32_16x16x32_bf16(a, bfrag[jb][kb], acc[jb], 0, 0, 0);
  }

  #pragma unroll
  for (int r = 0; r < 4; ++r) {
    float dv = dinv[row0 + q * 4 + r];
    #pragma unroll
    for (int jb = 0; jb < 4; ++jb)
      h1s[(row0 + q * 4 + r) * 64 + jb * 16 + m] = f2bf(acc[jb][r] * dv);
  }
}

// Fused sort + layer-1 aggregate + MFMA GEMM2. Block = bucket (512 thr).
// Gather: quarter-wave per node; within a quarter, lanes split hl=ql>>3 over
// an edge PAIR; fl=ql&7 is the uint4 (16B) slice of the 128B row. One load
// instruction covers 2 edges. Halves combined once via shfl_xor(8,16).
__global__ __launch_bounds__(512) void kagg1f(
    const u16* __restrict__ h1s, const int* __restrict__ etmp,
    const int* __restrict__ cursor, const float* __restrict__ dinv,
    const float* __restrict__ b1f, const u16* __restrict__ W2b,
    int* __restrict__ esort, int2* __restrict__ rowse,
    u16* __restrict__ h2sb, int N) {
  __shared__ int eL[CAP];                 // staging; reused as f32 rows tile
  __shared__ int eS[CAP];                 // sorted src indices
  __shared__ int hist[128], starts[128], curs[128];
  __shared__ float sdinv[128];

  int tid = threadIdx.x;
  int bk = blockIdx.x;
  int base = bk * CAP;
  int cnt = cursor[bk];
  int node0 = bk << 7;

  if (tid < 128) {
    hist[tid] = 0;
    int nd = node0 + tid;
    sdinv[tid] = (nd < N) ? dinv[nd] : 0.f;
  }
  __syncthreads();
  for (int i = tid; i < cnt; i += 512) {
    int pk = etmp[base + i];
    eL[i] = pk;
    atomicAdd(&hist[pk & 127], 1);
  }
  __syncthreads();
  if (tid < 64) {
    int v0 = hist[tid], v1 = hist[tid + 64];
    int s0 = v0;
    #pragma unroll
    for (int off = 1; off < 64; off <<= 1) {
      int t = __shfl_up(s0, off, 64);
      if (tid >= off) s0 += t;
    }
    int tot0 = __shfl(s0, 63, 64);
    int s1 = v1;
    #pragma unroll
    for (int off = 1; off < 64; off <<= 1) {
      int t = __shfl_up(s1, off, 64);
      if (tid >= off) s1 += t;
    }
    s1 += tot0;
    int e0x = s0 - v0, e1x = s1 - v1;
    starts[tid] = e0x;  curs[tid] = e0x;
    starts[tid + 64] = e1x;  curs[tid + 64] = e1x;
    int n0 = node0 + tid, n1 = n0 + 64;
    if (n0 < N) rowse[n0] = make_int2(base + e0x, base + e0x + v0);
    if (n1 < N) rowse[n1] = make_int2(base + e1x, base + e1x + v1);
  }
  __syncthreads();
  for (int i = tid; i < cnt; i += 512) {
    int pk = eL[i];
    int pos = atomicAdd(&curs[pk & 127], 1);
    int sidx = pk >> 7;
    eS[pos] = sidx;
    esort[base + pos] = sidx;
  }

  // GEMM2 B-frags (W2b row-major [k][class]); lane&15 = class column.
  int lane = tid & 63, wv = tid >> 6;
  int m16 = lane & 15, q = lane >> 4;
  short8 bw0, bw1;
  #pragma unroll
  for (int j = 0; j < 8; ++j) {
    bw0[j] = (short)W2b[(q * 8 + j) * 16 + m16];
    bw1[j] = (short)W2b[(32 + q * 8 + j) * 16 + m16];
  }
  __syncthreads();                        // eS/starts/hist final; eL now free

  float* rowsL = (float*)eL;              // [32 rows][68 stride] f32 (8.7 KB)
  const uint4* h1u = (const uint4*)h1s;   // 8 uint4 per 64-feat row
  int fl = m16 & 7, hl = m16 >> 3;
  int wrow = wv * 4 + q;                  // WAVE-LOCAL staging row (0..31)

  for (int pass = 0; pass < 4; ++pass) {
    int nl = pass * 32 + wv * 4 + q;
    int nd = node0 + nl;
    int cn = (nd < N) ? nd : node0;
    int rs = starts[nl], ke = rs + hist[nl];
    float a0 = 0.f, a1 = 0.f, a2 = 0.f, a3 = 0.f;
    float a4 = 0.f, a5 = 0.f, a6 = 0.f, a7 = 0.f;
    int k = rs;
    for (; k + 8 <= ke; k += 8) {         // 4 loads (8 edges) in flight
      int i0 = eS[k + hl], i1 = eS[k + 2 + hl];
      int i2 = eS[k + 4 + hl], i3 = eS[k + 6 + hl];
      uint4 g0 = h1u[i0 * 8 + fl];
      uint4 g1 = h1u[i1 * 8 + fl];
      uint4 g2 = h1u[i2 * 8 + fl];
      uint4 g3 = h1u[i3 * 8 + fl];
      a0 += bf2f((u16)(g0.x & 0xffff)) + bf2f((u16)(g1.x & 0xffff))
          + bf2f((u16)(g2.x & 0xffff)) + bf2f((u16)(g3.x & 0xffff));
      a1 += bf2f((u16)(g0.x >> 16)) + bf2f((u16)(g1.x >> 16))
          + bf2f((u16)(g2.x >> 16)) + bf2f((u16)(g3.x >> 16));
      a2 += bf2f((u16)(g0.y & 0xffff)) + bf2f((u16)(g1.y & 0xffff))
          + bf2f((u16)(g2.y & 0xffff)) + bf2f((u16)(g3.y & 0xffff));
      a3 += bf2f((u16)(g0.y >> 16)) + bf2f((u16)(g1.y >> 16))
          + bf2f((u16)(g2.y >> 16)) + bf2f((u16)(g3.y >> 16));
      a4 += bf2f((u16)(g0.z & 0xffff)) + bf2f((u16)(g1.z & 0xffff))
          + bf2f((u16)(g2.z & 0xffff)) + bf2f((u16)(g3.z & 0xffff));
      a5 += bf2f((u16)(g0.z >> 16)) + bf2f((u16)(g1.z >> 16))
          + bf2f((u16)(g2.z >> 16)) + bf2f((u16)(g3.z >> 16));
      a6 += bf2f((u16)(g0.w & 0xffff)) + bf2f((u16)(g1.w & 0xffff))
          + bf2f((u16)(g2.w & 0xffff)) + bf2f((u16)(g3.w & 0xffff));
      a7 += bf2f((u16)(g0.w >> 16)) + bf2f((u16)(g1.w >> 16))
          + bf2f((u16)(g2.w >> 16)) + bf2f((u16)(g3.w >> 16));
    }
    for (; k < ke; k += 2) {              // tail pairs (maybe ragged)
      int e = k + hl;
      bool valid = e < ke;
      uint4 g = h1u[eS[valid ? e : (ke - 1)] * 8 + fl];
      if (valid) {
        a0 += bf2f((u16)(g.x & 0xffff));  a1 += bf2f((u16)(g.x >> 16));
        a2 += bf2f((u16)(g.y & 0xffff));  a3 += bf2f((u16)(g.y >> 16));
        a4 += bf2f((u16)(g.z & 0xffff));  a5 += bf2f((u16)(g.z >> 16));
        a6 += bf2f((u16)(g.w & 0xffff));  a7 += bf2f((u16)(g.w >> 16));
      }
    }
    // combine the two edge-parity halves (lanes differing in bit3 of ql)
    a0 += __shfl_xor(a0, 8, 16);  a1 += __shfl_xor(a1, 8, 16);
    a2 += __shfl_xor(a2, 8, 16);  a3 += __shfl_xor(a3, 8, 16);
    a4 += __shfl_xor(a4, 8, 16);  a5 += __shfl_xor(a5, 8, 16);
    a6 += __shfl_xor(a6, 8, 16);  a7 += __shfl_xor(a7, 8, 16);

    uint4 sg = h1u[cn * 8 + fl];
    float dv = sdinv[nl];
    float4 ba = ((const float4*)b1f)[2 * fl];
    float4 bb = ((const float4*)b1f)[2 * fl + 1];
    float v0 = fmaxf(dv * (a0 + bf2f((u16)(sg.x & 0xffff))) + ba.x, 0.f);
    float v1 = fmaxf(dv * (a1 + bf2f((u16)(sg.x >> 16))) + ba.y, 0.f);
    float v2 = fmaxf(dv * (a2 + bf2f((u16)(sg.y & 0xffff))) + ba.z, 0.f);
    float v3 = fmaxf(dv * (a3 + bf2f((u16)(sg.y >> 16))) + ba.w, 0.f);
    float v4 = fmaxf(dv * (a4 + bf2f((u16)(sg.z & 0xffff))) + bb.x, 0.f);
    float v5 = fmaxf(dv * (a5 + bf2f((u16)(sg.z >> 16))) + bb.y, 0.f);
    float v6 = fmaxf(dv * (a6 + bf2f((u16)(sg.w & 0xffff))) + bb.z, 0.f);
    float v7 = fmaxf(dv * (a7 + bf2f((u16)(sg.w >> 16))) + bb.w, 0.f);

    if (hl == 0) {                        // 8 lanes cover the 64-feat row
      float* rp = &rowsL[wrow * 68 + 8 * fl];     // WAVE-LOCAL row (R11 fix)
      *(float4*)rp = make_float4(v0, v1, v2, v3);
      *(float4*)(rp + 4) = make_float4(v4, v5, v6, v7);
    }
    __builtin_amdgcn_wave_barrier();      // order LDS write->read in-wave

    // MFMA GEMM2: A[m=lane&15 -> wave row (mod 4)][k=q*8+j] from rowsL.
    const float* ar = &rowsL[(wv * 4 + (m16 & 3)) * 68];
    bool rv = (m16 < 4);
    short8 af0, af1;
    #pragma unroll
    for (int j = 0; j < 8; ++j) {
      af0[j] = rv ? (short)f2bf(ar[q * 8 + j]) : (short)0;
      af1[j] = rv ? (short)f2bf(ar[32 + q * 8 + j]) : (short)0;
    }
    f32x4 c = (f32x4){0.f, 0.f, 0.f, 0.f};
    c = __builtin_amdgcn_mfma_f32_16x16x32_bf16(af0, bw0, c, 0, 0, 0);
    c = __builtin_amdgcn_mfma_f32_16x16x32_bf16(af1, bw1, c, 0, 0, 0);
    if (q == 0) {
      #pragma unroll
      for (int r = 0; r < 4; ++r) {
        int nl2 = pass * 32 + wv * 4 + r;
        int nd2 = node0 + nl2;
        if (nd2 < N) h2sb[nd2 * 16 + m16] = f2bf(c[r] * sdinv[nl2]);
      }
    }
    __builtin_amdgcn_wave_barrier();      // keep next pass's write after reads
  }
}

// Layer-2 aggregate + bias + relu + log_softmax.
// OCT per node; hl=(lane>>2)&1 = edge parity, fl=lane&3 = uint2 slice of the
// 32B row -> one load instr = 2 edges. Width-4 softmax over 16 classes.
__global__ __launch_bounds__(256) void kagg2(
    const u16* __restrict__ h2sb, const int* __restrict__ esort,
    const int2* __restrict__ rowse, const float* __restrict__ dinv,
    const float* __restrict__ b2f, const int* __restrict__ mode,
    void* __restrict__ out, int n) {
  int mflag = mode[0];
  int tid = threadIdx.x;
  int lane = tid & 63, wv = tid >> 6;
  int oc = lane >> 3, ol = lane & 7;
  int hl = ol >> 2, fl = ol & 3;
  int node = blockIdx.x * 32 + wv * 8 + oc;
  if (node >= n) node = n - 1;
  int2 se = rowse[node];
  int beg = se.x, end = se.y;
  const uint2* h2v = (const uint2*)h2sb;   // 4 uint2 per 16-class row
  uint2 sg = h2v[node * 4 + fl];
  float a0 = 0.f, a1 = 0.f, a2 = 0.f, a3 = 0.f;

  int k = beg;
  for (; k + 8 <= end; k += 8) {           // 4 loads (8 edges) in flight
    int i0 = esort[k + hl], i1 = esort[k + 2 + hl];
    int i2 = esort[k + 4 + hl], i3 = esort[k + 6 + hl];
    uint2 g0 = h2v[i0 * 4 + fl];
    uint2 g1 = h2v[i1 * 4 + fl];
    uint2 g2 = h2v[i2 * 4 + fl];
    uint2 g3 = h2v[i3 * 4 + fl];
    a0 += bf2f((u16)(g0.x & 0xffff)) + bf2f((u16)(g1.x & 0xffff))
        + bf2f((u16)(g2.x & 0xffff)) + bf2f((u16)(g3.x & 0xffff));
    a1 += bf2f((u16)(g0.x >> 16)) + bf2f((u16)(g1.x >> 16))
        + bf2f((u16)(g2.x >> 16)) + bf2f((u16)(g3.x >> 16));
    a2 += bf2f((u16)(g0.y & 0xffff)) + bf2f((u16)(g1.y & 0xffff))
        + bf2f((u16)(g2.y & 0xffff)) + bf2f((u16)(g3.y & 0xffff));
    a3 += bf2f((u16)(g0.y >> 16)) + bf2f((u16)(g1.y >> 16))
        + bf2f((u16)(g2.y >> 16)) + bf2f((u16)(g3.y >> 16));
  }
  for (; k < end; k += 2) {
    int e = k + hl;
    bool valid = e < end;
    uint2 g = h2v[esort[valid ? e : (end - 1)] * 4 + fl];
    if (valid) {
      a0 += bf2f((u16)(g.x & 0xffff));  a1 += bf2f((u16)(g.x >> 16));
      a2 += bf2f((u16)(g.y & 0xffff));  a3 += bf2f((u16)(g.y >> 16));
    }
  }
  // combine edge-parity halves (lanes +-4 within the oct)
  a0 += __shfl_xor(a0, 4, 8);  a1 += __shfl_xor(a1, 4, 8);
  a2 += __shfl_xor(a2, 4, 8);  a3 += __shfl_xor(a3, 4, 8);

  float dv = dinv[node];
  float4 bv = ((const float4*)b2f)[fl];
  float v0 = fmaxf(dv * (a0 + bf2f((u16)(sg.x & 0xffff))) + bv.x, 0.f);
  float v1 = fmaxf(dv * (a1 + bf2f((u16)(sg.x >> 16))) + bv.y, 0.f);
  float v2 = fmaxf(dv * (a2 + bf2f((u16)(sg.y & 0xffff))) + bv.z, 0.f);
  float v3 = fmaxf(dv * (a3 + bf2f((u16)(sg.y >> 16))) + bv.w, 0.f);

  float m = fmaxf(fmaxf(v0, v1), fmaxf(v2, v3));
  m = fmaxf(m, __shfl_xor(m, 1, 4));
  m = fmaxf(m, __shfl_xor(m, 2, 4));
  float ex = __expf(v0 - m) + __expf(v1 - m) + __expf(v2 - m) + __expf(v3 - m);
  ex += __shfl_xor(ex, 1, 4);
  ex += __shfl_xor(ex, 2, 4);
  float lg = __logf(ex);
  float r0 = v0 - m - lg, r1 = v1 - m - lg;
  float r2 = v2 - m - lg, r3 = v3 - m - lg;
  if (hl == 0) {
    if (mflag) {
      ((float4*)out)[(size_t)node * 4 + fl] = make_float4(r0, r1, r2, r3);
    } else {
      uint2 o;
      o.x = (unsigned int)f2bf(r0) | ((unsigned int)f2bf(r1) << 16);
      o.y = (unsigned int)f2bf(r2) | ((unsigned int)f2bf(r3) << 16);
      ((uint2*)out)[(size_t)node * 4 + fl] = o;
    }
  }
}

extern "C" void kernel_launch(void* const* d_in, const int* in_sizes, int n_in,
                              void* d_out, int out_size, void* d_ws, size_t ws_size,
                              hipStream_t stream) {
  const void* x  = d_in[0];
  const int* ei  = (const int*)d_in[1];
  const void* W1 = d_in[2];
  const void* b1 = d_in[3];
  const void* W2 = d_in[4];
  const void* b2 = d_in[5];

  const int N = in_sizes[0] / 128;
  const int E = in_sizes[1] / 2;
  const int* src = ei;
  const int* dst = ei + E;
  const int NB = (N + 127) >> 7;          // 128-node buckets

  char* ws = (char*)d_ws;
  size_t off = 0;
  auto alloc = [&](size_t bytes) -> char* {
    char* p = ws + off;
    off = (off + bytes + 255) & ~(size_t)255;
    return p;
  };
  u16*   h1s    = (u16*)  alloc((size_t)N * 64 * 2);
  u16*   h2sb   = (u16*)  alloc((size_t)N * 16 * 2);
  int*   etmp   = (int*)  alloc((size_t)NB * CAP * 4);
  int*   esort  = (int*)  alloc((size_t)NB * CAP * 4);
  int2*  rowse  = (int2*) alloc((size_t)N * 8);
  float* dinv   = (float*)alloc((size_t)N * 4);
  int*   cursor = (int*)  alloc((size_t)NB * 4);
  u16*   W1b    = (u16*)  alloc(8192 * 2);
  u16*   W2b    = (u16*)  alloc(1024 * 2);
  float* b1f    = (float*)alloc(64 * 4);
  float* b2f    = (float*)alloc(16 * 4);
  int*   mode   = (int*)  alloc(4);

  hipMemsetAsync(cursor, 0, (size_t)NB * 4, stream);

  int pblocks = (E + 8191) / 8192;
  kpartc<<<pblocks + 1, 512, 0, stream>>>(src, dst, cursor, etmp,
                                          W1, b1, W2, b2,
                                          W1b, b1f, W2b, b2f, mode, E, NB);
  kfine<<<NB, 512, 0, stream>>>(etmp, cursor, dinv, N);

  int tiles = (N + 15) / 16;
  kgemm1<<<(tiles + 3) / 4, 256, 0, stream>>>(x, W1b, mode, dinv, h1s, N);
  kagg1f<<<NB, 512, 0, stream>>>(h1s, etmp, cursor, dinv, b1f, W2b,
                                 esort, rowse, h2sb, N);
  kagg2<<<(N + 31) / 32, 256, 0, stream>>>(h2sb, esort, rowse, dinv, b2f, mode,
                                           d_out, N);
}

// Round 13
// 196.738 us; speedup vs baseline: 5.0014x; 1.0043x over previous
//
#include <hip/hip_runtime.h>
#include <hip/hip_bf16.h>

// GCN 2-layer forward for MI355X (gfx950).
// Dtype detected on-device (f32 vs bf16 harness conversion), inside kpartc b0.
// Rows pre-scaled by dinv so aggregation is a plain sum.
// LESSONS: (R5,R9) LDS-atomic scatter aggregation is ~10x slower than register
// accumulation. (R10) fuse the counting sort into the gather kernel. (R11)
// rowsL staging must be wave-local. (R12) uint4 edge-pair gathers regress:
// fewer load instrs but same cache lines + extra shfls — uint2/lane is optimal.
// Pipeline (5 dispatches):
//   kpartc : block0 = weight canonicalization + dtype detect; other blocks
//            partition edges -> etmp[bk*CAP+slot] packed (src<<7)|dstlow
//   kgemm1f: block per bucket: histogram etmp -> dinv; then h1s = (x@W1)*dinv
//            (MFMA, 8 waves x 16-row tiles)  [kfine fused in]
//   kagg1f : block per bucket: LDS counting sort -> eS; quarter-wave per node
//            register gather (uint2 8B/lane, 16 lanes/row, 8 in flight);
//            MFMA GEMM2 epilogue -> h2sb; emits esort+rowse
//   kagg2  : oct per node, uint2 slice, edge-pairs; width-4 softmax -> out

typedef unsigned short u16;
typedef __attribute__((ext_vector_type(8))) short short8;   // 8 bf16
typedef __attribute__((ext_vector_type(4))) float f32x4;

#define CAP 4096    // bucket capacity: Binomial(1.6M, 1/782) ~ 2046 +- 45

__device__ __forceinline__ float bf2f(u16 u) {
  return __uint_as_float(((unsigned int)u) << 16);
}
__device__ __forceinline__ u16 f2bf(float f) {
  unsigned int u = __float_as_uint(f);
  u += 0x7fffu + ((u >> 16) & 1u);
  return (u16)(u >> 16);
}

// ---- merged: block 0 = weight canonicalization + dtype detect;
//      blocks 1.. = edge partition into padded buckets (8192 edges/block) ----
__global__ __launch_bounds__(512) void kpartc(
    const int* __restrict__ src, const int* __restrict__ dst,
    int* __restrict__ cursor, int* __restrict__ etmp,
    const void* __restrict__ W1r, const void* __restrict__ b1r,
    const void* __restrict__ W2r, const void* __restrict__ b2r,
    u16* __restrict__ W1b, float* __restrict__ b1f, u16* __restrict__ W2b,
    float* __restrict__ b2f, int* __restrict__ mode, int E, int NB) {
  __shared__ int hist[1024], basep[1024];
  __shared__ float red[8];
  __shared__ int smode;
  int tid = threadIdx.x;

  if (blockIdx.x == 0) {
    // ---- conv role ----
    const u16* w = (const u16*)W1r;
    float mx = 0.f;
    for (int i = tid; i < 8192; i += 512) {
      float av = fabsf(bf2f(w[i]));
      if (!(av <= 1e6f)) av = 3e38f;
      mx = fmaxf(mx, av);
    }
    #pragma unroll
    for (int off = 32; off >= 1; off >>= 1) mx = fmaxf(mx, __shfl_xor(mx, off, 64));
    if ((tid & 63) == 0) red[tid >> 6] = mx;
    __syncthreads();
    if (tid == 0) {
      float m2 = 0.f;
      #pragma unroll
      for (int wv = 0; wv < 8; ++wv) m2 = fmaxf(m2, red[wv]);
      smode = (m2 > 1e6f) ? 1 : 0;
      mode[0] = smode;
    }
    __syncthreads();
    int m = smode;
    for (int i = tid; i < 8192; i += 512)
      W1b[i] = m ? f2bf(((const float*)W1r)[i]) : ((const u16*)W1r)[i];
    for (int i = tid; i < 1024; i += 512)
      W2b[i] = m ? f2bf(((const float*)W2r)[i]) : ((const u16*)W2r)[i];
    if (tid < 64) b1f[tid] = m ? ((const float*)b1r)[tid] : bf2f(((const u16*)b1r)[tid]);
    if (tid < 16) b2f[tid] = m ? ((const float*)b2r)[tid] : bf2f(((const u16*)b2r)[tid]);
    return;
  }

  // ---- partition role ----
  for (int i = tid; i < 1024; i += 512) hist[i] = 0;
  __syncthreads();
  int e0 = (blockIdx.x - 1) * 8192 + tid * 16;
  int pk[16], off[16], cb[16];
  if (e0 + 15 < E) {
    int4 s4[4], d4[4];
    #pragma unroll
    for (int u = 0; u < 4; ++u) {
      s4[u] = ((const int4*)(src + e0))[u];
      d4[u] = ((const int4*)(dst + e0))[u];
    }
    const int* sp = (const int*)s4;
    const int* dp = (const int*)d4;
    #pragma unroll
    for (int k = 0; k < 16; ++k) {
      int s = sp[k], d = dp[k];
      cb[k] = d >> 7;
      pk[k] = (s << 7) | (d & 127);
      off[k] = atomicAdd(&hist[cb[k]], 1);
    }
  } else {
    #pragma unroll
    for (int k = 0; k < 16; ++k) {
      int e = e0 + k;
      cb[k] = -1;
      if (e < E) {
        int s = src[e], d = dst[e];
        cb[k] = d >> 7;
        pk[k] = (s << 7) | (d & 127);
        off[k] = atomicAdd(&hist[cb[k]], 1);
      }
    }
  }
  __syncthreads();
  for (int i = tid; i < NB; i += 512)
    if (hist[i]) basep[i] = atomicAdd(&cursor[i], hist[i]);
  __syncthreads();
  if (e0 + 15 < E) {
    #pragma unroll
    for (int k = 0; k < 16; ++k)
      etmp[cb[k] * CAP + basep[cb[k]] + off[k]] = pk[k];
  } else {
    #pragma unroll
    for (int k = 0; k < 16; ++k)
      if (cb[k] >= 0) etmp[cb[k] * CAP + basep[cb[k]] + off[k]] = pk[k];
  }
}

// Fused: per bucket histogram -> dinv, then h1s = (x @ W1) * dinv (MFMA).
// Block = bucket (512 thr = 8 waves); wave wv does rows [node0+wv*16, +16).
__global__ __launch_bounds__(512) void kgemm1f(
    const void* __restrict__ xraw, const u16* __restrict__ W1b,
    const int* __restrict__ mode, const int* __restrict__ etmp,
    const int* __restrict__ cursor, float* __restrict__ dinv,
    u16* __restrict__ h1s, int N) {
  __shared__ int hist[128];
  __shared__ float sdinv[128];
  int tid = threadIdx.x;
  int bk = blockIdx.x;
  int base = bk * CAP;
  int cnt = cursor[bk];
  int node0 = bk << 7;

  if (tid < 128) hist[tid] = 0;
  __syncthreads();
  for (int i = tid; i < cnt; i += 512)
    atomicAdd(&hist[etmp[base + i] & 127], 1);
  __syncthreads();
  if (tid < 128) {
    float dv = rsqrtf((float)(hist[tid] + 1));
    sdinv[tid] = dv;
    int nd = node0 + tid;
    if (nd < N) dinv[nd] = dv;
  }
  __syncthreads();

  int mflag = mode[0];
  int lane = tid & 63, wv = tid >> 6;
  int m = lane & 15, q = lane >> 4;
  int row0 = node0 + wv * 16;

  short8 bfrag[4][4];
  for (int jb = 0; jb < 4; ++jb)
    for (int kb = 0; kb < 4; ++kb) {
      short8 f;
      #pragma unroll
      for (int j = 0; j < 8; ++j)
        f[j] = (short)W1b[(kb * 32 + q * 8 + j) * 64 + jb * 16 + m];
      bfrag[jb][kb] = f;
    }

  f32x4 acc[4];
  #pragma unroll
  for (int jb = 0; jb < 4; ++jb) acc[jb] = (f32x4){0.f, 0.f, 0.f, 0.f};

  int rowm = row0 + m;
  size_t rc = (size_t)((rowm < N) ? rowm : (N - 1));   // clamp loads only
  #pragma unroll
  for (int kb = 0; kb < 4; ++kb) {
    short8 a;
    if (mflag) {
      const float* xf = (const float*)xraw + rc * 128 + kb * 32 + q * 8;
      float4 u0 = ((const float4*)xf)[0];
      float4 u1 = ((const float4*)xf)[1];
      __hip_bfloat162 p0 = __float22bfloat162_rn(make_float2(u0.x, u0.y));
      __hip_bfloat162 p1 = __float22bfloat162_rn(make_float2(u0.z, u0.w));
      __hip_bfloat162 p2 = __float22bfloat162_rn(make_float2(u1.x, u1.y));
      __hip_bfloat162 p3 = __float22bfloat162_rn(make_float2(u1.z, u1.w));
      unsigned int w0 = *(const unsigned int*)&p0;
      unsigned int w1 = *(const unsigned int*)&p1;
      unsigned int w2 = *(const unsigned int*)&p2;
      unsigned int w3 = *(const unsigned int*)&p3;
      a[0] = (short)(w0 & 0xffff); a[1] = (short)(w0 >> 16);
      a[2] = (short)(w1 & 0xffff); a[3] = (short)(w1 >> 16);
      a[4] = (short)(w2 & 0xffff); a[5] = (short)(w2 >> 16);
      a[6] = (short)(w3 & 0xffff); a[7] = (short)(w3 >> 16);
    } else {
      a = *(const short8*)((const u16*)xraw + rc * 128 + kb * 32 + q * 8);
    }
    #pragma unroll
    for (int jb = 0; jb < 4; ++jb)
      acc[jb] = __builtin_amdgcn_mfma_f32_16x16x32_bf16(a, bfrag[jb][kb], acc[jb], 0, 0, 0);
  }

  #pragma unroll
  for (int r = 0; r < 4; ++r) {
    int rr = row0 + q * 4 + r;
    if (rr < N) {
      float dv = sdinv[wv * 16 + q * 4 + r];
      #pragma unroll
      for (int jb = 0; jb < 4; ++jb)
        h1s[(size_t)rr * 64 + jb * 16 + m] = f2bf(acc[jb][r] * dv);
    }
  }
}

// Fused sort + layer-1 aggregate + MFMA GEMM2. Block = bucket (512 thr).
// Gather (R10-proven): quarter-wave per node; lane ql owns features
// 4ql..4ql+3 (uint2 8B slice); 8 independent gathers in flight.
__global__ __launch_bounds__(512) void kagg1f(
    const u16* __restrict__ h1s, const int* __restrict__ etmp,
    const int* __restrict__ cursor, const float* __restrict__ dinv,
    const float* __restrict__ b1f, const u16* __restrict__ W2b,
    int* __restrict__ esort, int2* __restrict__ rowse,
    u16* __restrict__ h2sb, int N) {
  __shared__ int eL[CAP];                 // staging; reused as f32 rows tile
  __shared__ int eS[CAP];                 // sorted src indices
  __shared__ int hist[128], starts[128], curs[128];
  __shared__ float sdinv[128];

  int tid = threadIdx.x;
  int bk = blockIdx.x;
  int base = bk * CAP;
  int cnt = cursor[bk];
  int node0 = bk << 7;

  if (tid < 128) {
    hist[tid] = 0;
    int nd = node0 + tid;
    sdinv[tid] = (nd < N) ? dinv[nd] : 0.f;
  }
  __syncthreads();
  for (int i = tid; i < cnt; i += 512) {
    int pk = etmp[base + i];
    eL[i] = pk;
    atomicAdd(&hist[pk & 127], 1);
  }
  __syncthreads();
  if (tid < 64) {
    int v0 = hist[tid], v1 = hist[tid + 64];
    int s0 = v0;
    #pragma unroll
    for (int off = 1; off < 64; off <<= 1) {
      int t = __shfl_up(s0, off, 64);
      if (tid >= off) s0 += t;
    }
    int tot0 = __shfl(s0, 63, 64);
    int s1 = v1;
    #pragma unroll
    for (int off = 1; off < 64; off <<= 1) {
      int t = __shfl_up(s1, off, 64);
      if (tid >= off) s1 += t;
    }
    s1 += tot0;
    int e0x = s0 - v0, e1x = s1 - v1;
    starts[tid] = e0x;  curs[tid] = e0x;
    starts[tid + 64] = e1x;  curs[tid + 64] = e1x;
    int n0 = node0 + tid, n1 = n0 + 64;
    if (n0 < N) rowse[n0] = make_int2(base + e0x, base + e0x + v0);
    if (n1 < N) rowse[n1] = make_int2(base + e1x, base + e1x + v1);
  }
  __syncthreads();
  for (int i = tid; i < cnt; i += 512) {
    int pk = eL[i];
    int pos = atomicAdd(&curs[pk & 127], 1);
    int sidx = pk >> 7;
    eS[pos] = sidx;
    esort[base + pos] = sidx;
  }

  // GEMM2 B-frags (W2b row-major [k][class]); lane&15 = class column.
  int lane = tid & 63, wv = tid >> 6;
  int m16 = lane & 15, q = lane >> 4;     // m16 doubles as ql (uint2 slice)
  short8 bw0, bw1;
  #pragma unroll
  for (int j = 0; j < 8; ++j) {
    bw0[j] = (short)W2b[(q * 8 + j) * 16 + m16];
    bw1[j] = (short)W2b[(32 + q * 8 + j) * 16 + m16];
  }
  __syncthreads();                        // eS/starts/hist final; eL now free

  float* rowsL = (float*)eL;              // [32 rows][68 stride] f32 (8.7 KB)
  const uint2* h1v = (const uint2*)h1s;   // 16 uint2 per 64-feat row
  int ql = m16;
  int wrow = wv * 4 + q;                  // WAVE-LOCAL staging row (0..31)

  for (int pass = 0; pass < 4; ++pass) {
    int nl = pass * 32 + wv * 4 + q;
    int nd = node0 + nl;
    int cn = (nd < N) ? nd : node0;
    int rs = starts[nl], ke = rs + hist[nl];
    float a0 = 0.f, a1 = 0.f, a2 = 0.f, a3 = 0.f;
    int k = rs;
    for (; k + 8 <= ke; k += 8) {         // 8 independent gathers in flight
      int sI[8];
      uint2 g[8];
      #pragma unroll
      for (int p = 0; p < 8; ++p) sI[p] = eS[k + p];
      #pragma unroll
      for (int p = 0; p < 8; ++p) g[p] = h1v[sI[p] * 16 + ql];
      #pragma unroll
      for (int p = 0; p < 8; ++p) {
        a0 += bf2f((u16)(g[p].x & 0xffff));
        a1 += bf2f((u16)(g[p].x >> 16));
        a2 += bf2f((u16)(g[p].y & 0xffff));
        a3 += bf2f((u16)(g[p].y >> 16));
      }
    }
    for (; k < ke; ++k) {
      int s = eS[k];
      uint2 g = h1v[s * 16 + ql];
      a0 += bf2f((u16)(g.x & 0xffff));
      a1 += bf2f((u16)(g.x >> 16));
      a2 += bf2f((u16)(g.y & 0xffff));
      a3 += bf2f((u16)(g.y >> 16));
    }
    uint2 sg = h1v[cn * 16 + ql];
    float dv = sdinv[nl];
    float4 bv = ((const float4*)b1f)[ql];
    float4 vr;
    vr.x = fmaxf(dv * (a0 + bf2f((u16)(sg.x & 0xffff))) + bv.x, 0.f);
    vr.y = fmaxf(dv * (a1 + bf2f((u16)(sg.x >> 16))) + bv.y, 0.f);
    vr.z = fmaxf(dv * (a2 + bf2f((u16)(sg.y & 0xffff))) + bv.z, 0.f);
    vr.w = fmaxf(dv * (a3 + bf2f((u16)(sg.y >> 16))) + bv.w, 0.f);

    // stage relu1 into the wave's PRIVATE 4-row tile (wave-local only)
    *(float4*)&rowsL[wrow * 68 + 4 * ql] = vr;
    __builtin_amdgcn_wave_barrier();      // order LDS write->read in-wave

    // MFMA GEMM2: A[m=lane&15 -> wave row (mod 4)][k=q*8+j] from rowsL.
    const float* ar = &rowsL[(wv * 4 + (m16 & 3)) * 68];
    bool rv = (m16 < 4);
    short8 af0, af1;
    #pragma unroll
    for (int j = 0; j < 8; ++j) {
      af0[j] = rv ? (short)f2bf(ar[q * 8 + j]) : (short)0;
      af1[j] = rv ? (short)f2bf(ar[32 + q * 8 + j]) : (short)0;
    }
    f32x4 c = (f32x4){0.f, 0.f, 0.f, 0.f};
    c = __builtin_amdgcn_mfma_f32_16x16x32_bf16(af0, bw0, c, 0, 0, 0);
    c = __builtin_amdgcn_mfma_f32_16x16x32_bf16(af1, bw1, c, 0, 0, 0);
    if (q == 0) {
      #pragma unroll
      for (int r = 0; r < 4; ++r) {
        int nl2 = pass * 32 + wv * 4 + r;
        int nd2 = node0 + nl2;
        if (nd2 < N) h2sb[nd2 * 16 + m16] = f2bf(c[r] * sdinv[nl2]);
      }
    }
    __builtin_amdgcn_wave_barrier();      // keep next pass's write after reads
  }
}

// Layer-2 aggregate + bias + relu + log_softmax.
// OCT per node; hl=(lane>>2)&1 = edge parity, fl=lane&3 = uint2 slice of the
// 32B row -> one load instr = 2 edges. Width-4 softmax over 16 classes.
__global__ __launch_bounds__(256) void kagg2(
    const u16* __restrict__ h2sb, const int* __restrict__ esort,
    const int2* __restrict__ rowse, const float* __restrict__ dinv,
    const float* __restrict__ b2f, const int* __restrict__ mode,
    void* __restrict__ out, int n) {
  int mflag = mode[0];
  int tid = threadIdx.x;
  int lane = tid & 63, wv = tid >> 6;
  int oc = lane >> 3, ol = lane & 7;
  int hl = ol >> 2, fl = ol & 3;
  int node = blockIdx.x * 32 + wv * 8 + oc;
  if (node >= n) node = n - 1;
  int2 se = rowse[node];
  int beg = se.x, end = se.y;
  const uint2* h2v = (const uint2*)h2sb;   // 4 uint2 per 16-class row
  uint2 sg = h2v[node * 4 + fl];
  float a0 = 0.f, a1 = 0.f, a2 = 0.f, a3 = 0.f;

  int k = beg;
  for (; k + 8 <= end; k += 8) {           // 4 loads (8 edges) in flight
    int i0 = esort[k + hl], i1 = esort[k + 2 + hl];
    int i2 = esort[k + 4 + hl], i3 = esort[k + 6 + hl];
    uint2 g0 = h2v[i0 * 4 + fl];
    uint2 g1 = h2v[i1 * 4 + fl];
    uint2 g2 = h2v[i2 * 4 + fl];
    uint2 g3 = h2v[i3 * 4 + fl];
    a0 += bf2f((u16)(g0.x & 0xffff)) + bf2f((u16)(g1.x & 0xffff))
        + bf2f((u16)(g2.x & 0xffff)) + bf2f((u16)(g3.x & 0xffff));
    a1 += bf2f((u16)(g0.x >> 16)) + bf2f((u16)(g1.x >> 16))
        + bf2f((u16)(g2.x >> 16)) + bf2f((u16)(g3.x >> 16));
    a2 += bf2f((u16)(g0.y & 0xffff)) + bf2f((u16)(g1.y & 0xffff))
        + bf2f((u16)(g2.y & 0xffff)) + bf2f((u16)(g3.y & 0xffff));
    a3 += bf2f((u16)(g0.y >> 16)) + bf2f((u16)(g1.y >> 16))
        + bf2f((u16)(g2.y >> 16)) + bf2f((u16)(g3.y >> 16));
  }
  for (; k < end; k += 2) {
    int e = k + hl;
    bool valid = e < end;
    uint2 g = h2v[esort[valid ? e : (end - 1)] * 4 + fl];
    if (valid) {
      a0 += bf2f((u16)(g.x & 0xffff));  a1 += bf2f((u16)(g.x >> 16));
      a2 += bf2f((u16)(g.y & 0xffff));  a3 += bf2f((u16)(g.y >> 16));
    }
  }
  // combine edge-parity halves (lanes +-4 within the oct)
  a0 += __shfl_xor(a0, 4, 8);  a1 += __shfl_xor(a1, 4, 8);
  a2 += __shfl_xor(a2, 4, 8);  a3 += __shfl_xor(a3, 4, 8);

  float dv = dinv[node];
  float4 bv = ((const float4*)b2f)[fl];
  float v0 = fmaxf(dv * (a0 + bf2f((u16)(sg.x & 0xffff))) + bv.x, 0.f);
  float v1 = fmaxf(dv * (a1 + bf2f((u16)(sg.x >> 16))) + bv.y, 0.f);
  float v2 = fmaxf(dv * (a2 + bf2f((u16)(sg.y & 0xffff))) + bv.z, 0.f);
  float v3 = fmaxf(dv * (a3 + bf2f((u16)(sg.y >> 16))) + bv.w, 0.f);

  float m = fmaxf(fmaxf(v0, v1), fmaxf(v2, v3));
  m = fmaxf(m, __shfl_xor(m, 1, 4));
  m = fmaxf(m, __shfl_xor(m, 2, 4));
  float ex = __expf(v0 - m) + __expf(v1 - m) + __expf(v2 - m) + __expf(v3 - m);
  ex += __shfl_xor(ex, 1, 4);
  ex += __shfl_xor(ex, 2, 4);
  float lg = __logf(ex);
  float r0 = v0 - m - lg, r1 = v1 - m - lg;
  float r2 = v2 - m - lg, r3 = v3 - m - lg;
  if (hl == 0) {
    if (mflag) {
      ((float4*)out)[(size_t)node * 4 + fl] = make_float4(r0, r1, r2, r3);
    } else {
      uint2 o;
      o.x = (unsigned int)f2bf(r0) | ((unsigned int)f2bf(r1) << 16);
      o.y = (unsigned int)f2bf(r2) | ((unsigned int)f2bf(r3) << 16);
      ((uint2*)out)[(size_t)node * 4 + fl] = o;
    }
  }
}

extern "C" void kernel_launch(void* const* d_in, const int* in_sizes, int n_in,
                              void* d_out, int out_size, void* d_ws, size_t ws_size,
                              hipStream_t stream) {
  const void* x  = d_in[0];
  const int* ei  = (const int*)d_in[1];
  const void* W1 = d_in[2];
  const void* b1 = d_in[3];
  const void* W2 = d_in[4];
  const void* b2 = d_in[5];

  const int N = in_sizes[0] / 128;
  const int E = in_sizes[1] / 2;
  const int* src = ei;
  const int* dst = ei + E;
  const int NB = (N + 127) >> 7;          // 128-node buckets

  char* ws = (char*)d_ws;
  size_t off = 0;
  auto alloc = [&](size_t bytes) -> char* {
    char* p = ws + off;
    off = (off + bytes + 255) & ~(size_t)255;
    return p;
  };
  u16*   h1s    = (u16*)  alloc((size_t)N * 64 * 2);
  u16*   h2sb   = (u16*)  alloc((size_t)N * 16 * 2);
  int*   etmp   = (int*)  alloc((size_t)NB * CAP * 4);
  int*   esort  = (int*)  alloc((size_t)NB * CAP * 4);
  int2*  rowse  = (int2*) alloc((size_t)N * 8);
  float* dinv   = (float*)alloc((size_t)N * 4);
  int*   cursor = (int*)  alloc((size_t)NB * 4);
  u16*   W1b    = (u16*)  alloc(8192 * 2);
  u16*   W2b    = (u16*)  alloc(1024 * 2);
  float* b1f    = (float*)alloc(64 * 4);
  float* b2f    = (float*)alloc(16 * 4);
  int*   mode   = (int*)  alloc(4);

  hipMemsetAsync(cursor, 0, (size_t)NB * 4, stream);

  int pblocks = (E + 8191) / 8192;
  kpartc<<<pblocks + 1, 512, 0, stream>>>(src, dst, cursor, etmp,
                                          W1, b1, W2, b2,
                                          W1b, b1f, W2b, b2f, mode, E, NB);
  kgemm1f<<<NB, 512, 0, stream>>>(x, W1b, mode, etmp, cursor, dinv, h1s, N);
  kagg1f<<<NB, 512, 0, stream>>>(h1s, etmp, cursor, dinv, b1f, W2b,
                                 esort, rowse, h2sb, N);
  kagg2<<<(N + 31) / 32, 256, 0, stream>>>(h2sb, esort, rowse, dinv, b2f, mode,
                                           d_out, N);
}